// Round 3
// baseline (6553.478 us; speedup 1.0000x reference)
//
#include <hip/hip_runtime.h>
#include <hip/hip_bf16.h>

#define N_NODES 100000
#define N_EDGES 2000000
#define EPS 1e-9f
#define NORMC 0.22360679774997896f  // 1/sqrt(20)

typedef short s8 __attribute__((ext_vector_type(8)));
typedef float f4 __attribute__((ext_vector_type(4)));

__device__ __forceinline__ float silu_f(float x) {
    return x / (1.0f + __expf(-x));
}

__device__ __forceinline__ ushort f2bfu(float f) {
    union { __hip_bfloat16 b; ushort u; } cv;
    cv.b = __float2bfloat16(f);
    return cv.u;
}

__device__ __forceinline__ uint pkbf(float lo, float hi) {
    float2 t; t.x = lo; t.y = hi;
    union { __hip_bfloat162 b; uint u; } cv;
    cv.b = __float22bfloat162_rn(t);
    return cv.u;
}

// ---------------------------------------------------------------------------
// Workspace (floats):
//   xn_norm : 3,200,000
//   acc1    : 3,200,000
//   acc2    : 3,200,000
//   MF      : 17,408 f32-slots (34816 bf16)  edge bilinear fragments
//   MG      : 17,408 f32-slots               e2n bilinear fragments
//   BpN     : 4,224
//   WxE     : 1,056
//   CtE     : 1,056
// MF/MG layout (ushort): [((kk*2+nt)*64 + lane)*8 + t], kk in [0,34):
//   kk<33 : value Mext[n][i=kk][j=kl];  kk==33 : Mext[n][i=kl][32]
//   n = nt*16 + (lane&15), kl = ((lane>>4)&3)*8 + t
// ---------------------------------------------------------------------------

__device__ float mext(const float* __restrict__ W, const float* __restrict__ B,
                      const float* __restrict__ bias, int n, int i, int j) {
    if (i < 32 && j < 32) {
        float r = 0.f;
        #pragma unroll
        for (int m = 0; m < 32; ++m) r += W[n*96 + 64 + m] * B[m*1024 + i*32 + j];
        return r;
    }
    if (i < 32) return W[n*96 + i];        // j == 32
    if (j < 32) return W[n*96 + 32 + j];   // i == 32
    return bias[n];
}

__global__ void prep_kernel(const float* __restrict__ W_n2e, const float* __restrict__ B_n2e,
                            const float* __restrict__ b_n2e,
                            const float* __restrict__ W_e2n, const float* __restrict__ B_e2n,
                            const float* __restrict__ b_e2n,
                            const float* __restrict__ W_mix_xn, const float* __restrict__ B_mix_xn,
                            const float* __restrict__ b_mix_xn,
                            const float* __restrict__ W_mix_xe, const float* __restrict__ B_mix_xe,
                            const float* __restrict__ b_mix_xe,
                            ushort* __restrict__ MF, ushort* __restrict__ MG,
                            float* __restrict__ BpN, float* __restrict__ WxE,
                            float* __restrict__ CtE) {
    int t = blockIdx.x * blockDim.x + threadIdx.x;
    if (t < 69632) {
        int u = (t < 34816) ? t : t - 34816;
        int tt = u & 7, lane = (u >> 3) & 63, rest = u >> 9;
        int nt = rest & 1, kk = rest >> 1;
        int n = nt*16 + (lane & 15);
        int kl = ((lane >> 4) & 3) * 8 + tt;
        int i, j;
        if (kk < 33) { i = kk; j = kl; } else { i = kl; j = 32; }
        if (t < 34816) MF[u] = f2bfu(mext(W_n2e, B_n2e, b_n2e, n, i, j));
        else           MG[u] = f2bfu(mext(W_e2n, B_e2n, b_e2n, n, i, j));
    } else if (t < 73856) {
        int u = t - 69632;
        int k = u & 31, ij = u >> 5;   // ij in [0,132)
        int i = ij >> 2, j = ij & 3;
        float r;
        if (i < 32 && j < 3) {
            r = 0.f;
            #pragma unroll
            for (int m = 0; m < 32; ++m) r += W_mix_xn[k*67 + 35 + m] * B_mix_xn[m*96 + i*3 + j];
        } else if (i < 32 && j == 3) {
            r = W_mix_xn[k*67 + i];
        } else if (i == 32 && j < 3) {
            r = W_mix_xn[k*67 + 32 + j];
        } else {
            r = b_mix_xn[k];
        }
        BpN[ij*32 + k] = r;
    } else if (t < 74912) {
        int u = t - 73856;
        int k = u & 31, i = u >> 5;    // i in [0,33)
        WxE[i*32 + k] = (i < 32) ? W_mix_xe[k*65 + i] : b_mix_xe[k];
    } else if (t < 75968) {
        int u = t - 74912;
        int k = u & 31, i = u >> 5;
        float r;
        if (i < 32) {
            r = 0.f;
            #pragma unroll
            for (int m = 0; m < 32; ++m) r += W_mix_xe[k*65 + 33 + m] * B_mix_xe[m*32 + i];
        } else {
            r = W_mix_xe[k*65 + 32];
        }
        CtE[i*32 + k] = r;
    }
}

__global__ void zero_kernel(float4* __restrict__ p, int n4) {
    int i = blockIdx.x * blockDim.x + threadIdx.x;
    int stride = gridDim.x * blockDim.x;
    float4 z = {0.f, 0.f, 0.f, 0.f};
    for (; i < n4; i += stride) p[i] = z;
}

__global__ __launch_bounds__(256) void node_kernel(
    const float* __restrict__ xn, const float* __restrict__ xn_attr,
    const float* __restrict__ BpN, float* __restrict__ xn_norm) {
    int n = blockIdx.x * 256 + threadIdx.x;
    if (n >= N_NODES) return;
    float x[33];
    const float4* xr = (const float4*)(xn + (size_t)n * 32);
    #pragma unroll
    for (int q = 0; q < 8; ++q) {
        float4 v = xr[q];
        x[q*4+0] = v.x; x[q*4+1] = v.y; x[q*4+2] = v.z; x[q*4+3] = v.w;
    }
    x[32] = 1.f;
    float at[4];
    at[0] = xn_attr[n*3]; at[1] = xn_attr[n*3+1]; at[2] = xn_attr[n*3+2]; at[3] = 1.f;

    float acc[32];
    #pragma unroll
    for (int k = 0; k < 32; ++k) acc[k] = 0.f;
    #pragma unroll
    for (int i = 0; i < 33; ++i) {
        #pragma unroll
        for (int j = 0; j < 4; ++j) {
            float s = x[i] * at[j];
            const float* bp = BpN + (i*4 + j) * 32;
            #pragma unroll
            for (int k = 0; k < 32; ++k) acc[k] = fmaf(bp[k], s, acc[k]);
        }
    }
    float mean = 0.f;
    #pragma unroll
    for (int k = 0; k < 32; ++k) mean += acc[k];
    mean *= (1.0f / 32.0f);
    float var = 0.f;
    #pragma unroll
    for (int k = 0; k < 32; ++k) { float d = acc[k] - mean; var += d * d; }
    var *= (1.0f / 31.0f);
    float inv = 1.0f / (sqrtf(var) + EPS);
    float4* out = (float4*)(xn_norm + (size_t)n * 32);
    #pragma unroll
    for (int q = 0; q < 8; ++q) {
        float4 v;
        v.x = acc[q*4+0]*inv; v.y = acc[q*4+1]*inv; v.z = acc[q*4+2]*inv; v.w = acc[q*4+3]*inv;
        out[q] = v;
    }
}

// Stage-1 extended bilinear via MFMA, M fragments in LDS.
// a_f: [256][33] f32 rows; ab: [256][72] ushort, [0..31]=b bf16, [32..63]=a bf16.
// Writes result (+bias) back into a_f[row][0..31]; a_f[row][32] stays 1.
__device__ __forceinline__ void gemm33(const ushort* __restrict__ sM,
                                       float* __restrict__ a_f,
                                       const ushort* __restrict__ ab,
                                       const float* __restrict__ biasv, int tid) {
    int lane = tid & 63, wv = tid >> 6;
    int m = lane & 15, h = lane >> 4;
    int base = wv * 64;
    float bfv[4][8];
    s8 araw[4];
    #pragma unroll
    for (int g = 0; g < 4; ++g) {
        const ushort* rp = &ab[(size_t)(base + g*16 + m) * 72];
        union { s8 v; ushort s[8]; } braw;
        braw.v = *(const s8*)&rp[h*8];
        #pragma unroll
        for (int t = 0; t < 8; ++t) {
            union { uint u; float f; } cv; cv.u = ((uint)braw.s[t]) << 16;
            bfv[g][t] = cv.f;
        }
        araw[g] = *(const s8*)&rp[32 + h*8];
    }
    f4 c[4][2];
    #pragma unroll
    for (int g = 0; g < 4; ++g) {
        c[g][0] = (f4){0.f, 0.f, 0.f, 0.f};
        c[g][1] = (f4){0.f, 0.f, 0.f, 0.f};
    }
    const s8* M8 = (const s8*)sM;
    #pragma unroll
    for (int kk = 0; kk < 33; ++kk) {
        s8 mf0 = M8[(kk*2 + 0)*64 + lane];
        s8 mf1 = M8[(kk*2 + 1)*64 + lane];
        #pragma unroll
        for (int g = 0; g < 4; ++g) {
            float as = a_f[(size_t)(base + g*16 + m) * 33 + kk];
            union { s8 v; uint u[4]; } af;
            #pragma unroll
            for (int t = 0; t < 4; ++t) af.u[t] = pkbf(as * bfv[g][2*t], as * bfv[g][2*t+1]);
            c[g][0] = __builtin_amdgcn_mfma_f32_16x16x32_bf16(af.v, mf0, c[g][0], 0, 0, 0);
            c[g][1] = __builtin_amdgcn_mfma_f32_16x16x32_bf16(af.v, mf1, c[g][1], 0, 0, 0);
        }
    }
    {   // K-step 33: A = a (bf16) directly, covers j==32 column
        s8 mf0 = M8[66*64 + lane];
        s8 mf1 = M8[67*64 + lane];
        #pragma unroll
        for (int g = 0; g < 4; ++g) {
            c[g][0] = __builtin_amdgcn_mfma_f32_16x16x32_bf16(araw[g], mf0, c[g][0], 0, 0, 0);
            c[g][1] = __builtin_amdgcn_mfma_f32_16x16x32_bf16(araw[g], mf1, c[g][1], 0, 0, 0);
        }
    }
    float b0 = biasv[m], b1 = biasv[16 + m];
    #pragma unroll
    for (int g = 0; g < 4; ++g) {
        int rowb = base + g*16 + h*4;
        #pragma unroll
        for (int r = 0; r < 4; ++r) {
            a_f[(size_t)(rowb + r) * 33 + m]      = c[g][0][r] + b0;
            a_f[(size_t)(rowb + r) * 33 + 16 + m] = c[g][1][r] + b1;
        }
    }
}

#define TILES_E 7813

__global__ __launch_bounds__(256, 1) void edge_kernel(
    const float* __restrict__ xn_norm, const float* __restrict__ xe_attr,
    const int* __restrict__ xe_src, const int* __restrict__ xe_dst,
    const float* __restrict__ W_fc1, const float* __restrict__ b_fc1,
    const float* __restrict__ W_fc2, const float* __restrict__ b_fc2,
    const ushort* __restrict__ MF, const float* __restrict__ biasE,
    const float* __restrict__ WxE, const float* __restrict__ CtE,
    float* __restrict__ acc1, float* __restrict__ acc2) {
    __shared__ __align__(16) ushort sM[34816];   // 69,632 B
    __shared__ __align__(16) float  a_f[256 * 33]; // 33,792 B
    __shared__ __align__(16) ushort ab[256 * 72];  // 36,864 B
    int tid = threadIdx.x;
    {   // stage M fragments once per block
        const float4* s4p = (const float4*)MF;
        float4* d4p = (float4*)sM;
        #pragma unroll
        for (int i = 0; i < 17; ++i) d4p[tid + i*256] = s4p[tid + i*256];
    }
    uint* ab32 = (uint*)ab;

    int t = blockIdx.x;
    // prefetch tile t into registers
    float attrP = 0.f; int srcP = 0, dstP = 0; bool okP = false;
    float4 gP[8], dP[8];
    {
        int e = t*256 + tid;
        okP = e < N_EDGES;
        int ec = okP ? e : 0;
        attrP = xe_attr[ec]; srcP = xe_src[ec]; dstP = xe_dst[ec];
        const float4* gp = (const float4*)(xn_norm + (size_t)srcP * 32);
        const float4* dp = (const float4*)(xn_norm + (size_t)dstP * 32);
        #pragma unroll
        for (int q = 0; q < 8; ++q) { gP[q] = gp[q]; dP[q] = dp[q]; }
    }

    for (; t < TILES_E; t += 256) {
        // ---- stage current tile into LDS
        float attr = attrP; int csrc = srcP, cdst = dstP; bool okC = okP;
        float vs = okC ? 1.f : 0.f;
        #pragma unroll
        for (int q = 0; q < 8; ++q) {
            float4 g = gP[q], d = dP[q];
            float gg[4] = {g.x, g.y, g.z, g.w};
            float dd[4] = {d.x, d.y, d.z, d.w};
            #pragma unroll
            for (int p = 0; p < 2; ++p) {
                int k = q*4 + p*2;
                float w0 = silu_f(attr * W_fc1[k]   + b_fc1[k])   * vs;
                float w1 = silu_f(attr * W_fc1[k+1] + b_fc1[k+1]) * vs;
                float av0 = w0 * (gg[2*p]   - dd[2*p]);
                float av1 = w1 * (gg[2*p+1] - dd[2*p+1]);
                float bv0 = w0 * (gg[2*p]   + dd[2*p])   * 0.5f;
                float bv1 = w1 * (gg[2*p+1] + dd[2*p+1]) * 0.5f;
                a_f[tid*33 + k]   = av0;
                a_f[tid*33 + k+1] = av1;
                ab32[tid*36 + (k>>1)]      = pkbf(bv0, bv1);
                ab32[tid*36 + 16 + (k>>1)] = pkbf(av0, av1);
            }
        }
        a_f[tid*33 + 32] = 1.f;

        // ---- prefetch next tile (hidden under gemm + epilogue)
        int tn = t + 256;
        if (tn < TILES_E) {
            int e = tn*256 + tid;
            okP = e < N_EDGES;
            int ec = okP ? e : 0;
            attrP = xe_attr[ec]; srcP = xe_src[ec]; dstP = xe_dst[ec];
            const float4* gp = (const float4*)(xn_norm + (size_t)srcP * 32);
            const float4* dp = (const float4*)(xn_norm + (size_t)dstP * 32);
            #pragma unroll
            for (int q = 0; q < 8; ++q) { gP[q] = gp[q]; dP[q] = dp[q]; }
        }
        __syncthreads();

        gemm33(sM, a_f, ab, biasE, tid);
        __syncthreads();

        // ---- mix_xe (f32, float2-packed) + std + scatter
        float2 y2[16];
        #pragma unroll
        for (int k2 = 0; k2 < 16; ++k2) y2[k2] = make_float2(0.f, 0.f);
        for (int i = 0; i < 33; ++i) {
            float xi = a_f[tid*33 + i];
            const float2* wx2 = (const float2*)(WxE + i * 32);
            const float2* ct2 = (const float2*)(CtE + i * 32);
            #pragma unroll
            for (int k2 = 0; k2 < 16; ++k2) {
                float2 w = wx2[k2], ctv = ct2[k2];
                float lx = fmaf(attr, ctv.x, w.x);
                float ly = fmaf(attr, ctv.y, w.y);
                y2[k2].x = fmaf(lx, xi, y2[k2].x);
                y2[k2].y = fmaf(ly, xi, y2[k2].y);
            }
        }
        float mean = 0.f;
        #pragma unroll
        for (int k2 = 0; k2 < 16; ++k2) mean += y2[k2].x + y2[k2].y;
        mean *= (1.0f / 32.0f);
        float var = 0.f;
        #pragma unroll
        for (int k2 = 0; k2 < 16; ++k2) {
            float dx = y2[k2].x - mean, dy = y2[k2].y - mean;
            var += dx*dx + dy*dy;
        }
        var *= (1.0f / 31.0f);
        float inv = 1.0f / (sqrtf(var) + EPS);

        if (okC) {
            float* p1 = acc1 + (size_t)cdst * 32;
            float* p2 = acc2 + (size_t)csrc * 32;
            #pragma unroll
            for (int k = 0; k < 32; ++k) {
                float yk = (k & 1) ? y2[k>>1].y : y2[k>>1].x;
                float w2 = silu_f(attr * W_fc2[k] + b_fc2[k]);
                float v = w2 * yk * inv;
                unsafeAtomicAdd(p1 + k, v);
                unsafeAtomicAdd(p2 + k, v);
            }
        }
    }
}

#define TILES_F 391

__global__ __launch_bounds__(256, 1) void final_kernel(
    const float* __restrict__ acc1, const float* __restrict__ acc2,
    const ushort* __restrict__ MG, const float* __restrict__ biasG,
    float* __restrict__ out) {
    __shared__ __align__(16) ushort sM[34816];
    __shared__ __align__(16) float  a_f[256 * 33];
    __shared__ __align__(16) ushort ab[256 * 72];
    int tid = threadIdx.x;
    {
        const float4* s4p = (const float4*)MG;
        float4* d4p = (float4*)sM;
        #pragma unroll
        for (int i = 0; i < 17; ++i) d4p[tid + i*256] = s4p[tid + i*256];
    }
    uint* ab32 = (uint*)ab;

    for (int t = blockIdx.x; t < TILES_F; t += 256) {
        int n = t*256 + tid;
        bool ok = n < N_NODES;
        int nn = ok ? n : 0;
        float vs = ok ? 1.f : 0.f;
        const float4* p1 = (const float4*)(acc1 + (size_t)nn * 32);
        const float4* p2 = (const float4*)(acc2 + (size_t)nn * 32);
        #pragma unroll
        for (int q = 0; q < 8; ++q) {
            float4 u1 = p1[q], u2 = p2[q];
            float a1[4] = {u1.x, u1.y, u1.z, u1.w};
            float a2[4] = {u2.x, u2.y, u2.z, u2.w};
            #pragma unroll
            for (int p = 0; p < 2; ++p) {
                int k = q*4 + p*2;
                float dv0 = (a1[2*p]   - a2[2*p])   * NORMC * vs;
                float dv1 = (a1[2*p+1] - a2[2*p+1]) * NORMC * vs;
                float sv0 = (a1[2*p]   + a2[2*p])   * NORMC * vs;
                float sv1 = (a1[2*p+1] + a2[2*p+1]) * NORMC * vs;
                a_f[tid*33 + k]   = dv0;
                a_f[tid*33 + k+1] = dv1;
                ab32[tid*36 + (k>>1)]      = pkbf(sv0, sv1);
                ab32[tid*36 + 16 + (k>>1)] = pkbf(dv0, dv1);
            }
        }
        a_f[tid*33 + 32] = 1.f;
        __syncthreads();

        gemm33(sM, a_f, ab, biasG, tid);
        __syncthreads();

        if (ok) {
            float z[32];
            float mean = 0.f;
            #pragma unroll
            for (int k = 0; k < 32; ++k) { z[k] = silu_f(a_f[tid*33 + k]); mean += z[k]; }
            mean *= (1.0f / 32.0f);
            float var = 0.f;
            #pragma unroll
            for (int k = 0; k < 32; ++k) { float d = z[k] - mean; var += d * d; }
            var *= (1.0f / 31.0f);
            float inv = 1.0f / (sqrtf(var) + EPS);
            float4* op = (float4*)(out + (size_t)n * 32);
            #pragma unroll
            for (int q = 0; q < 8; ++q) {
                float4 v;
                v.x = z[q*4+0]*inv; v.y = z[q*4+1]*inv; v.z = z[q*4+2]*inv; v.w = z[q*4+3]*inv;
                op[q] = v;
            }
        }
    }
}

extern "C" void kernel_launch(void* const* d_in, const int* in_sizes, int n_in,
                              void* d_out, int out_size, void* d_ws, size_t ws_size,
                              hipStream_t stream) {
    const float* xn       = (const float*)d_in[0];
    const float* xn_attr  = (const float*)d_in[1];
    const float* xe_attr  = (const float*)d_in[2];
    const int*   xe_src   = (const int*)d_in[3];
    const int*   xe_dst   = (const int*)d_in[4];
    const float* W_fc1    = (const float*)d_in[5];
    const float* b_fc1    = (const float*)d_in[6];
    const float* W_fc2    = (const float*)d_in[7];
    const float* b_fc2    = (const float*)d_in[8];
    const float* B_mix_xn = (const float*)d_in[9];
    const float* W_mix_xn = (const float*)d_in[10];
    const float* b_mix_xn = (const float*)d_in[11];
    const float* B_n2e    = (const float*)d_in[12];
    const float* W_n2e    = (const float*)d_in[13];
    const float* b_n2e    = (const float*)d_in[14];
    const float* B_mix_xe = (const float*)d_in[15];
    const float* W_mix_xe = (const float*)d_in[16];
    const float* b_mix_xe = (const float*)d_in[17];
    const float* B_e2n    = (const float*)d_in[18];
    const float* W_e2n    = (const float*)d_in[19];
    const float* b_e2n    = (const float*)d_in[20];

    float* ws      = (float*)d_ws;
    float* xn_norm = ws;
    float* acc1    = ws + 3200000;
    float* acc2    = ws + 6400000;
    ushort* MF     = (ushort*)(ws + 9600000);
    ushort* MG     = MF + 34816;
    float* BpN     = ws + 9600000 + 34816;   // after 2*17408 f32-slots for MF+MG
    float* WxE     = BpN + 4224;
    float* CtE     = WxE + 1056;

    prep_kernel<<<297, 256, 0, stream>>>(W_n2e, B_n2e, b_n2e,
                                         W_e2n, B_e2n, b_e2n,
                                         W_mix_xn, B_mix_xn, b_mix_xn,
                                         W_mix_xe, B_mix_xe, b_mix_xe,
                                         MF, MG, BpN, WxE, CtE);
    zero_kernel<<<2048, 256, 0, stream>>>((float4*)acc1, 1600000);
    node_kernel<<<391, 256, 0, stream>>>(xn, xn_attr, BpN, xn_norm);
    edge_kernel<<<256, 256, 0, stream>>>(xn_norm, xe_attr, xe_src, xe_dst,
                                         W_fc1, b_fc1, W_fc2, b_fc2,
                                         MF, b_n2e, WxE, CtE, acc1, acc2);
    final_kernel<<<256, 256, 0, stream>>>(acc1, acc2, MG, b_e2n, (float*)d_out);
}

// Round 4
// 1727.685 us; speedup vs baseline: 3.7932x; 3.7932x over previous
//
#include <hip/hip_runtime.h>
#include <hip/hip_bf16.h>

#define N_NODES 100000
#define N_EDGES 2000000
#define EPS 1e-9f
#define NORMC 0.22360679774997896f  // 1/sqrt(20)

// bucketing geometry
#define BKSZ   512                  // nodes per bucket
#define NBK1   196                  // buckets per side (196*512 = 100,352 >= 100,000)
#define NBK    392                  // total buckets (dst side + src side)
#define NSB    512                  // scatter/count blocks
#define CE     3907                 // edges per scatter block (512*3907 >= 2M)
#define NITEMS 4000000              // 2 * N_EDGES

typedef short s8 __attribute__((ext_vector_type(8)));
typedef float f4 __attribute__((ext_vector_type(4)));

__device__ __forceinline__ float silu_f(float x) {
    return x / (1.0f + __expf(-x));
}

__device__ __forceinline__ ushort f2bfu(float f) {
    union { __hip_bfloat16 b; ushort u; } cv;
    cv.b = __float2bfloat16(f);
    return cv.u;
}

__device__ __forceinline__ uint pkbf(float lo, float hi) {
    float2 t; t.x = lo; t.y = hi;
    union { __hip_bfloat162 b; uint u; } cv;
    cv.b = __float22bfloat162_rn(t);
    return cv.u;
}

// ---------------------------------------------------------------------------
// MAIN workspace layout (f32 slots):
//   0          xn_norm   3,200,000
//   3,200,000  sd0       3,211,264   (100,352 x 32)  segment sums over dst
//   6,411,264  sd1       3,211,264                   segment sums over src
//   9,622,528  MF        17,408      (34,816 bf16)
//   9,639,936  MG        17,408
//   9,657,344  BpN        4,224
//   9,661,568  WxE        1,056
//   9,662,624  CtE        1,056
//   9,663,680  wxe       32,000,000  (64,000,000 bf16 = 2M x 32)
//   41,663,680 bucketed   4,000,000  (int)
//   45,663,680 cntg         200,704  (int)
//   45,864,384 scang        200,704  (int)
//   total 46,065,088 f32 = 184,260,352 B
// FALLBACK (atomic) layout = round-3 layout (38,564,608 B).
// ---------------------------------------------------------------------------

__device__ float mext(const float* __restrict__ W, const float* __restrict__ B,
                      const float* __restrict__ bias, int n, int i, int j) {
    if (i < 32 && j < 32) {
        float r = 0.f;
        #pragma unroll
        for (int m = 0; m < 32; ++m) r += W[n*96 + 64 + m] * B[m*1024 + i*32 + j];
        return r;
    }
    if (i < 32) return W[n*96 + i];        // j == 32
    if (j < 32) return W[n*96 + 32 + j];   // i == 32
    return bias[n];
}

__global__ void prep_kernel(const float* __restrict__ W_n2e, const float* __restrict__ B_n2e,
                            const float* __restrict__ b_n2e,
                            const float* __restrict__ W_e2n, const float* __restrict__ B_e2n,
                            const float* __restrict__ b_e2n,
                            const float* __restrict__ W_mix_xn, const float* __restrict__ B_mix_xn,
                            const float* __restrict__ b_mix_xn,
                            const float* __restrict__ W_mix_xe, const float* __restrict__ B_mix_xe,
                            const float* __restrict__ b_mix_xe,
                            ushort* __restrict__ MF, ushort* __restrict__ MG,
                            float* __restrict__ BpN, float* __restrict__ WxE,
                            float* __restrict__ CtE) {
    int t = blockIdx.x * blockDim.x + threadIdx.x;
    if (t < 69632) {
        int u = (t < 34816) ? t : t - 34816;
        int tt = u & 7, lane = (u >> 3) & 63, rest = u >> 9;
        int nt = rest & 1, kk = rest >> 1;
        int n = nt*16 + (lane & 15);
        int kl = ((lane >> 4) & 3) * 8 + tt;
        int i, j;
        if (kk < 33) { i = kk; j = kl; } else { i = kl; j = 32; }
        if (t < 34816) MF[u] = f2bfu(mext(W_n2e, B_n2e, b_n2e, n, i, j));
        else           MG[u] = f2bfu(mext(W_e2n, B_e2n, b_e2n, n, i, j));
    } else if (t < 73856) {
        int u = t - 69632;
        int k = u & 31, ij = u >> 5;   // ij in [0,132)
        int i = ij >> 2, j = ij & 3;
        float r;
        if (i < 32 && j < 3) {
            r = 0.f;
            #pragma unroll
            for (int m = 0; m < 32; ++m) r += W_mix_xn[k*67 + 35 + m] * B_mix_xn[m*96 + i*3 + j];
        } else if (i < 32 && j == 3) {
            r = W_mix_xn[k*67 + i];
        } else if (i == 32 && j < 3) {
            r = W_mix_xn[k*67 + 32 + j];
        } else {
            r = b_mix_xn[k];
        }
        BpN[ij*32 + k] = r;
    } else if (t < 74912) {
        int u = t - 73856;
        int k = u & 31, i = u >> 5;    // i in [0,33)
        WxE[i*32 + k] = (i < 32) ? W_mix_xe[k*65 + i] : b_mix_xe[k];
    } else if (t < 75968) {
        int u = t - 74912;
        int k = u & 31, i = u >> 5;
        float r;
        if (i < 32) {
            r = 0.f;
            #pragma unroll
            for (int m = 0; m < 32; ++m) r += W_mix_xe[k*65 + 33 + m] * B_mix_xe[m*32 + i];
        } else {
            r = W_mix_xe[k*65 + 32];
        }
        CtE[i*32 + k] = r;
    }
}

__global__ void zero_kernel(float4* __restrict__ p, int n4) {
    int i = blockIdx.x * blockDim.x + threadIdx.x;
    int stride = gridDim.x * blockDim.x;
    float4 z = {0.f, 0.f, 0.f, 0.f};
    for (; i < n4; i += stride) p[i] = z;
}

__global__ __launch_bounds__(256) void node_kernel(
    const float* __restrict__ xn, const float* __restrict__ xn_attr,
    const float* __restrict__ BpN, float* __restrict__ xn_norm) {
    int n = blockIdx.x * 256 + threadIdx.x;
    if (n >= N_NODES) return;
    float x[33];
    const float4* xr = (const float4*)(xn + (size_t)n * 32);
    #pragma unroll
    for (int q = 0; q < 8; ++q) {
        float4 v = xr[q];
        x[q*4+0] = v.x; x[q*4+1] = v.y; x[q*4+2] = v.z; x[q*4+3] = v.w;
    }
    x[32] = 1.f;
    float at[4];
    at[0] = xn_attr[n*3]; at[1] = xn_attr[n*3+1]; at[2] = xn_attr[n*3+2]; at[3] = 1.f;

    float acc[32];
    #pragma unroll
    for (int k = 0; k < 32; ++k) acc[k] = 0.f;
    #pragma unroll
    for (int i = 0; i < 33; ++i) {
        #pragma unroll
        for (int j = 0; j < 4; ++j) {
            float s = x[i] * at[j];
            const float* bp = BpN + (i*4 + j) * 32;
            #pragma unroll
            for (int k = 0; k < 32; ++k) acc[k] = fmaf(bp[k], s, acc[k]);
        }
    }
    float mean = 0.f;
    #pragma unroll
    for (int k = 0; k < 32; ++k) mean += acc[k];
    mean *= (1.0f / 32.0f);
    float var = 0.f;
    #pragma unroll
    for (int k = 0; k < 32; ++k) { float d = acc[k] - mean; var += d * d; }
    var *= (1.0f / 31.0f);
    float inv = 1.0f / (sqrtf(var) + EPS);
    float4* out = (float4*)(xn_norm + (size_t)n * 32);
    #pragma unroll
    for (int q = 0; q < 8; ++q) {
        float4 v;
        v.x = acc[q*4+0]*inv; v.y = acc[q*4+1]*inv; v.z = acc[q*4+2]*inv; v.w = acc[q*4+3]*inv;
        out[q] = v;
    }
}

// ------------------------- CSR-free bucketing ------------------------------

__global__ __launch_bounds__(256) void count_kernel(
    const int* __restrict__ xe_src, const int* __restrict__ xe_dst,
    int* __restrict__ cntg) {
    __shared__ int cnt[NBK];
    int tid = threadIdx.x, b = blockIdx.x;
    for (int k = tid; k < NBK; k += 256) cnt[k] = 0;
    __syncthreads();
    int e0 = b * CE;
    for (int i = tid; i < CE; i += 256) {
        int e = e0 + i;
        if (e < N_EDGES) {
            atomicAdd(&cnt[xe_dst[e] >> 9], 1);
            atomicAdd(&cnt[NBK1 + (xe_src[e] >> 9)], 1);
        }
    }
    __syncthreads();
    for (int k = tid; k < NBK; k += 256) cntg[k * NSB + b] = cnt[k];
}

__global__ __launch_bounds__(1024) void scan_kernel(
    const int* __restrict__ cntg, int* __restrict__ scang) {
    __shared__ int part[1024];
    int t = threadIdx.x;
    const int CHUNK = 196;          // 1024*196 = 200,704 = NBK*NSB exactly
    int base = t * CHUNK;
    int s = 0;
    for (int i = 0; i < CHUNK; ++i) s += cntg[base + i];
    part[t] = s;
    __syncthreads();
    for (int off = 1; off < 1024; off <<= 1) {
        int v = part[t];
        int add = (t >= off) ? part[t - off] : 0;
        __syncthreads();
        part[t] = v + add;
        __syncthreads();
    }
    int run = (t == 0) ? 0 : part[t - 1];
    for (int i = 0; i < CHUNK; ++i) {
        int c = cntg[base + i];
        scang[base + i] = run;
        run += c;
    }
}

__global__ __launch_bounds__(256) void scatter_kernel(
    const int* __restrict__ xe_src, const int* __restrict__ xe_dst,
    const int* __restrict__ scang, int* __restrict__ bucketed) {
    __shared__ int cur[NBK];
    int tid = threadIdx.x, b = blockIdx.x;
    for (int k = tid; k < NBK; k += 256) cur[k] = scang[k * NSB + b];
    __syncthreads();
    int e0 = b * CE;
    for (int i = tid; i < CE; i += 256) {
        int e = e0 + i;
        if (e < N_EDGES) {
            int d = xe_dst[e];
            int p = atomicAdd(&cur[d >> 9], 1);
            bucketed[p] = e | ((d & 511) << 21);
            int s_ = xe_src[e];
            p = atomicAdd(&cur[NBK1 + (s_ >> 9)], 1);
            bucketed[p] = e | ((s_ & 511) << 21);
        }
    }
}

__global__ __launch_bounds__(256) void gather_kernel(
    const ushort* __restrict__ wxe, const int* __restrict__ bucketed,
    const int* __restrict__ scang, float* __restrict__ sd0) {
    __shared__ float accs[BKSZ * 33];     // 67,584 B, padded: bank=(node+k)&31
    int tid = threadIdx.x, bk = blockIdx.x;
    for (int i = tid; i < BKSZ * 33; i += 256) accs[i] = 0.f;
    __syncthreads();
    int start = scang[bk * NSB];
    int end = (bk == NBK - 1) ? NITEMS : scang[(bk + 1) * NSB];
    for (int i = start + tid; i < end; i += 256) {
        int p = bucketed[i];
        int e = p & 0x1FFFFF;
        int ln = (p >> 21) & 511;
        const uint4* wp = (const uint4*)(wxe + (size_t)e * 32);
        float* ap = &accs[ln * 33];
        #pragma unroll
        for (int q = 0; q < 4; ++q) {
            uint4 w = wp[q];
            uint uu[4] = {w.x, w.y, w.z, w.w};
            #pragma unroll
            for (int c = 0; c < 4; ++c) {
                uint u = uu[c];
                float lo = __uint_as_float((u & 0xFFFFu) << 16);
                float hi = __uint_as_float(u & 0xFFFF0000u);
                int k = q * 8 + c * 2;
                atomicAdd(&ap[k], lo);
                atomicAdd(&ap[k + 1], hi);
            }
        }
    }
    __syncthreads();
    int side = (bk < NBK1) ? 0 : 1;
    int nb = side ? bk - NBK1 : bk;
    float* out = sd0 + (size_t)side * 3211264 + (size_t)nb * BKSZ * 32;
    for (int i = tid; i < BKSZ * 32; i += 256) {
        int node = i >> 5, k = i & 31;
        out[i] = accs[node * 33 + k];
    }
}

// ------------------------- edge bilinear (MFMA) ----------------------------

// Stage-1 extended bilinear via MFMA, M fragments in LDS.
__device__ __forceinline__ void gemm33(const ushort* __restrict__ sM,
                                       float* __restrict__ a_f,
                                       const ushort* __restrict__ ab,
                                       const float* __restrict__ biasv, int tid) {
    int lane = tid & 63, wv = tid >> 6;
    int m = lane & 15, h = lane >> 4;
    int base = wv * 64;
    float bfv[4][8];
    s8 araw[4];
    #pragma unroll
    for (int g = 0; g < 4; ++g) {
        const ushort* rp = &ab[(size_t)(base + g*16 + m) * 72];
        union { s8 v; ushort s[8]; } braw;
        braw.v = *(const s8*)&rp[h*8];
        #pragma unroll
        for (int t = 0; t < 8; ++t) {
            union { uint u; float f; } cv; cv.u = ((uint)braw.s[t]) << 16;
            bfv[g][t] = cv.f;
        }
        araw[g] = *(const s8*)&rp[32 + h*8];
    }
    f4 c[4][2];
    #pragma unroll
    for (int g = 0; g < 4; ++g) {
        c[g][0] = (f4){0.f, 0.f, 0.f, 0.f};
        c[g][1] = (f4){0.f, 0.f, 0.f, 0.f};
    }
    const s8* M8 = (const s8*)sM;
    #pragma unroll
    for (int kk = 0; kk < 33; ++kk) {
        s8 mf0 = M8[(kk*2 + 0)*64 + lane];
        s8 mf1 = M8[(kk*2 + 1)*64 + lane];
        #pragma unroll
        for (int g = 0; g < 4; ++g) {
            float as = a_f[(size_t)(base + g*16 + m) * 33 + kk];
            union { s8 v; uint u[4]; } af;
            #pragma unroll
            for (int t = 0; t < 4; ++t) af.u[t] = pkbf(as * bfv[g][2*t], as * bfv[g][2*t+1]);
            c[g][0] = __builtin_amdgcn_mfma_f32_16x16x32_bf16(af.v, mf0, c[g][0], 0, 0, 0);
            c[g][1] = __builtin_amdgcn_mfma_f32_16x16x32_bf16(af.v, mf1, c[g][1], 0, 0, 0);
        }
    }
    {   // K-step 33: A = a (bf16) directly, covers j==32 column
        s8 mf0 = M8[66*64 + lane];
        s8 mf1 = M8[67*64 + lane];
        #pragma unroll
        for (int g = 0; g < 4; ++g) {
            c[g][0] = __builtin_amdgcn_mfma_f32_16x16x32_bf16(araw[g], mf0, c[g][0], 0, 0, 0);
            c[g][1] = __builtin_amdgcn_mfma_f32_16x16x32_bf16(araw[g], mf1, c[g][1], 0, 0, 0);
        }
    }
    float b0 = biasv[m], b1 = biasv[16 + m];
    #pragma unroll
    for (int g = 0; g < 4; ++g) {
        int rowb = base + g*16 + h*4;
        #pragma unroll
        for (int r = 0; r < 4; ++r) {
            a_f[(size_t)(rowb + r) * 33 + m]      = c[g][0][r] + b0;
            a_f[(size_t)(rowb + r) * 33 + 16 + m] = c[g][1][r] + b1;
        }
    }
}

#define TILES_E 7813

// STORE=true: write bf16 wxe rows. STORE=false: legacy global atomics.
template<bool STORE>
__global__ __launch_bounds__(256, 1) void edge_kernel(
    const float* __restrict__ xn_norm, const float* __restrict__ xe_attr,
    const int* __restrict__ xe_src, const int* __restrict__ xe_dst,
    const float* __restrict__ W_fc1, const float* __restrict__ b_fc1,
    const float* __restrict__ W_fc2, const float* __restrict__ b_fc2,
    const ushort* __restrict__ MF, const float* __restrict__ biasE,
    const float* __restrict__ WxE, const float* __restrict__ CtE,
    float* __restrict__ acc1, float* __restrict__ acc2,
    ushort* __restrict__ wxe) {
    __shared__ __align__(16) ushort sM[34816];     // 69,632 B
    __shared__ __align__(16) float  a_f[256 * 33]; // 33,792 B
    __shared__ __align__(16) ushort ab[256 * 72];  // 36,864 B
    int tid = threadIdx.x;
    {   // stage M fragments once per block
        const float4* s4p = (const float4*)MF;
        float4* d4p = (float4*)sM;
        #pragma unroll
        for (int i = 0; i < 17; ++i) d4p[tid + i*256] = s4p[tid + i*256];
    }
    uint* ab32 = (uint*)ab;

    int t = blockIdx.x;
    float attrP = 0.f; int srcP = 0, dstP = 0; bool okP = false;
    float4 gP[8], dP[8];
    {
        int e = t*256 + tid;
        okP = e < N_EDGES;
        int ec = okP ? e : 0;
        attrP = xe_attr[ec]; srcP = xe_src[ec]; dstP = xe_dst[ec];
        const float4* gp = (const float4*)(xn_norm + (size_t)srcP * 32);
        const float4* dp = (const float4*)(xn_norm + (size_t)dstP * 32);
        #pragma unroll
        for (int q = 0; q < 8; ++q) { gP[q] = gp[q]; dP[q] = dp[q]; }
    }

    for (; t < TILES_E; t += 256) {
        float attr = attrP; int csrc = srcP, cdst = dstP; bool okC = okP;
        float vs = okC ? 1.f : 0.f;
        #pragma unroll
        for (int q = 0; q < 8; ++q) {
            float4 g = gP[q], d = dP[q];
            float gg[4] = {g.x, g.y, g.z, g.w};
            float dd[4] = {d.x, d.y, d.z, d.w};
            #pragma unroll
            for (int p = 0; p < 2; ++p) {
                int k = q*4 + p*2;
                float w0 = silu_f(attr * W_fc1[k]   + b_fc1[k])   * vs;
                float w1 = silu_f(attr * W_fc1[k+1] + b_fc1[k+1]) * vs;
                float av0 = w0 * (gg[2*p]   - dd[2*p]);
                float av1 = w1 * (gg[2*p+1] - dd[2*p+1]);
                float bv0 = w0 * (gg[2*p]   + dd[2*p])   * 0.5f;
                float bv1 = w1 * (gg[2*p+1] + dd[2*p+1]) * 0.5f;
                a_f[tid*33 + k]   = av0;
                a_f[tid*33 + k+1] = av1;
                ab32[tid*36 + (k>>1)]      = pkbf(bv0, bv1);
                ab32[tid*36 + 16 + (k>>1)] = pkbf(av0, av1);
            }
        }
        a_f[tid*33 + 32] = 1.f;

        int tn = t + 256;
        if (tn < TILES_E) {
            int e = tn*256 + tid;
            okP = e < N_EDGES;
            int ec = okP ? e : 0;
            attrP = xe_attr[ec]; srcP = xe_src[ec]; dstP = xe_dst[ec];
            const float4* gp = (const float4*)(xn_norm + (size_t)srcP * 32);
            const float4* dp = (const float4*)(xn_norm + (size_t)dstP * 32);
            #pragma unroll
            for (int q = 0; q < 8; ++q) { gP[q] = gp[q]; dP[q] = dp[q]; }
        }
        __syncthreads();

        gemm33(sM, a_f, ab, biasE, tid);
        __syncthreads();

        // mix_xe folded: y = (Wx + attr*Ct) @ [xe1;1]
        float2 y2[16];
        #pragma unroll
        for (int k2 = 0; k2 < 16; ++k2) y2[k2] = make_float2(0.f, 0.f);
        for (int i = 0; i < 33; ++i) {
            float xi = a_f[tid*33 + i];
            const float2* wx2 = (const float2*)(WxE + i * 32);
            const float2* ct2 = (const float2*)(CtE + i * 32);
            #pragma unroll
            for (int k2 = 0; k2 < 16; ++k2) {
                float2 w = wx2[k2], ctv = ct2[k2];
                float lx = fmaf(attr, ctv.x, w.x);
                float ly = fmaf(attr, ctv.y, w.y);
                y2[k2].x = fmaf(lx, xi, y2[k2].x);
                y2[k2].y = fmaf(ly, xi, y2[k2].y);
            }
        }
        float mean = 0.f;
        #pragma unroll
        for (int k2 = 0; k2 < 16; ++k2) mean += y2[k2].x + y2[k2].y;
        mean *= (1.0f / 32.0f);
        float var = 0.f;
        #pragma unroll
        for (int k2 = 0; k2 < 16; ++k2) {
            float dx = y2[k2].x - mean, dy = y2[k2].y - mean;
            var += dx*dx + dy*dy;
        }
        var *= (1.0f / 31.0f);
        float inv = 1.0f / (sqrtf(var) + EPS);

        if (okC) {
            if (STORE) {
                uint pkv[16];
                #pragma unroll
                for (int k2 = 0; k2 < 16; ++k2) {
                    float w20 = silu_f(attr * W_fc2[2*k2]   + b_fc2[2*k2]);
                    float w21 = silu_f(attr * W_fc2[2*k2+1] + b_fc2[2*k2+1]);
                    pkv[k2] = pkbf(w20 * y2[k2].x * inv, w21 * y2[k2].y * inv);
                }
                uint4* wp = (uint4*)(wxe + (size_t)(t*256 + tid) * 32);
                #pragma unroll
                for (int q = 0; q < 4; ++q) {
                    uint4 v; v.x = pkv[q*4]; v.y = pkv[q*4+1]; v.z = pkv[q*4+2]; v.w = pkv[q*4+3];
                    wp[q] = v;
                }
            } else {
                float* p1 = acc1 + (size_t)cdst * 32;
                float* p2 = acc2 + (size_t)csrc * 32;
                #pragma unroll
                for (int k = 0; k < 32; ++k) {
                    float yk = (k & 1) ? y2[k>>1].y : y2[k>>1].x;
                    float w2 = silu_f(attr * W_fc2[k] + b_fc2[k]);
                    float v = w2 * yk * inv;
                    unsafeAtomicAdd(p1 + k, v);
                    unsafeAtomicAdd(p2 + k, v);
                }
            }
        }
    }
}

#define TILES_F 391

__global__ __launch_bounds__(256, 1) void final_kernel(
    const float* __restrict__ acc1, const float* __restrict__ acc2,
    const ushort* __restrict__ MG, const float* __restrict__ biasG,
    float* __restrict__ out) {
    __shared__ __align__(16) ushort sM[34816];
    __shared__ __align__(16) float  a_f[256 * 33];
    __shared__ __align__(16) ushort ab[256 * 72];
    int tid = threadIdx.x;
    {
        const float4* s4p = (const float4*)MG;
        float4* d4p = (float4*)sM;
        #pragma unroll
        for (int i = 0; i < 17; ++i) d4p[tid + i*256] = s4p[tid + i*256];
    }
    uint* ab32 = (uint*)ab;

    for (int t = blockIdx.x; t < TILES_F; t += 256) {
        int n = t*256 + tid;
        bool ok = n < N_NODES;
        int nn = ok ? n : 0;
        float vs = ok ? 1.f : 0.f;
        const float4* p1 = (const float4*)(acc1 + (size_t)nn * 32);
        const float4* p2 = (const float4*)(acc2 + (size_t)nn * 32);
        #pragma unroll
        for (int q = 0; q < 8; ++q) {
            float4 u1 = p1[q], u2 = p2[q];
            float a1[4] = {u1.x, u1.y, u1.z, u1.w};
            float a2[4] = {u2.x, u2.y, u2.z, u2.w};
            #pragma unroll
            for (int p = 0; p < 2; ++p) {
                int k = q*4 + p*2;
                float dv0 = (a1[2*p]   - a2[2*p])   * NORMC * vs;
                float dv1 = (a1[2*p+1] - a2[2*p+1]) * NORMC * vs;
                float sv0 = (a1[2*p]   + a2[2*p])   * NORMC * vs;
                float sv1 = (a1[2*p+1] + a2[2*p+1]) * NORMC * vs;
                a_f[tid*33 + k]   = dv0;
                a_f[tid*33 + k+1] = dv1;
                ab32[tid*36 + (k>>1)]      = pkbf(sv0, sv1);
                ab32[tid*36 + 16 + (k>>1)] = pkbf(dv0, dv1);
            }
        }
        a_f[tid*33 + 32] = 1.f;
        __syncthreads();

        gemm33(sM, a_f, ab, biasG, tid);
        __syncthreads();

        if (ok) {
            float z[32];
            float mean = 0.f;
            #pragma unroll
            for (int k = 0; k < 32; ++k) { z[k] = silu_f(a_f[tid*33 + k]); mean += z[k]; }
            mean *= (1.0f / 32.0f);
            float var = 0.f;
            #pragma unroll
            for (int k = 0; k < 32; ++k) { float d = z[k] - mean; var += d * d; }
            var *= (1.0f / 31.0f);
            float inv = 1.0f / (sqrtf(var) + EPS);
            float4* op = (float4*)(out + (size_t)n * 32);
            #pragma unroll
            for (int q = 0; q < 8; ++q) {
                float4 v;
                v.x = z[q*4+0]*inv; v.y = z[q*4+1]*inv; v.z = z[q*4+2]*inv; v.w = z[q*4+3]*inv;
                op[q] = v;
            }
        }
    }
}

extern "C" void kernel_launch(void* const* d_in, const int* in_sizes, int n_in,
                              void* d_out, int out_size, void* d_ws, size_t ws_size,
                              hipStream_t stream) {
    const float* xn       = (const float*)d_in[0];
    const float* xn_attr  = (const float*)d_in[1];
    const float* xe_attr  = (const float*)d_in[2];
    const int*   xe_src   = (const int*)d_in[3];
    const int*   xe_dst   = (const int*)d_in[4];
    const float* W_fc1    = (const float*)d_in[5];
    const float* b_fc1    = (const float*)d_in[6];
    const float* W_fc2    = (const float*)d_in[7];
    const float* b_fc2    = (const float*)d_in[8];
    const float* B_mix_xn = (const float*)d_in[9];
    const float* W_mix_xn = (const float*)d_in[10];
    const float* b_mix_xn = (const float*)d_in[11];
    const float* B_n2e    = (const float*)d_in[12];
    const float* W_n2e    = (const float*)d_in[13];
    const float* b_n2e    = (const float*)d_in[14];
    const float* B_mix_xe = (const float*)d_in[15];
    const float* W_mix_xe = (const float*)d_in[16];
    const float* b_mix_xe = (const float*)d_in[17];
    const float* B_e2n    = (const float*)d_in[18];
    const float* W_e2n    = (const float*)d_in[19];
    const float* b_e2n    = (const float*)d_in[20];

    float* ws = (float*)d_ws;
    const size_t MAIN_BYTES = 46065088ULL * 4ULL;
    bool big = ws_size >= MAIN_BYTES;

    if (big) {
        float*  xn_norm = ws;
        float*  sd0     = ws + 3200000;
        float*  sd1     = ws + 6411264;
        ushort* MF      = (ushort*)(ws + 9622528);
        ushort* MG      = MF + 34816;
        float*  BpN     = ws + 9657344;
        float*  WxE     = ws + 9661568;
        float*  CtE     = ws + 9662624;
        ushort* wxe     = (ushort*)(ws + 9663680);
        int*    bucketed= (int*)(ws + 41663680);
        int*    cntg    = (int*)(ws + 45663680);
        int*    scang   = (int*)(ws + 45864384);

        prep_kernel<<<297, 256, 0, stream>>>(W_n2e, B_n2e, b_n2e, W_e2n, B_e2n, b_e2n,
                                             W_mix_xn, B_mix_xn, b_mix_xn,
                                             W_mix_xe, B_mix_xe, b_mix_xe,
                                             MF, MG, BpN, WxE, CtE);
        node_kernel<<<391, 256, 0, stream>>>(xn, xn_attr, BpN, xn_norm);
        count_kernel<<<NSB, 256, 0, stream>>>(xe_src, xe_dst, cntg);
        scan_kernel<<<1, 1024, 0, stream>>>(cntg, scang);
        scatter_kernel<<<NSB, 256, 0, stream>>>(xe_src, xe_dst, scang, bucketed);
        edge_kernel<true><<<256, 256, 0, stream>>>(xn_norm, xe_attr, xe_src, xe_dst,
                                                   W_fc1, b_fc1, W_fc2, b_fc2,
                                                   MF, b_n2e, WxE, CtE,
                                                   nullptr, nullptr, wxe);
        gather_kernel<<<NBK, 256, 0, stream>>>(wxe, bucketed, scang, sd0);
        final_kernel<<<391, 256, 0, stream>>>(sd0, sd1, MG, b_e2n, (float*)d_out);
    } else {
        // fallback: round-3 atomic path (38.6 MB workspace)
        float*  xn_norm = ws;
        float*  acc1    = ws + 3200000;
        float*  acc2    = ws + 6400000;
        ushort* MF      = (ushort*)(ws + 9600000);
        ushort* MG      = MF + 34816;
        float*  BpN     = ws + 9600000 + 34816;
        float*  WxE     = BpN + 4224;
        float*  CtE     = WxE + 1056;

        prep_kernel<<<297, 256, 0, stream>>>(W_n2e, B_n2e, b_n2e, W_e2n, B_e2n, b_e2n,
                                             W_mix_xn, B_mix_xn, b_mix_xn,
                                             W_mix_xe, B_mix_xe, b_mix_xe,
                                             MF, MG, BpN, WxE, CtE);
        zero_kernel<<<2048, 256, 0, stream>>>((float4*)acc1, 1600000);
        node_kernel<<<391, 256, 0, stream>>>(xn, xn_attr, BpN, xn_norm);
        edge_kernel<false><<<256, 256, 0, stream>>>(xn_norm, xe_attr, xe_src, xe_dst,
                                                    W_fc1, b_fc1, W_fc2, b_fc2,
                                                    MF, b_n2e, WxE, CtE,
                                                    acc1, acc2, nullptr);
        final_kernel<<<391, 256, 0, stream>>>(acc1, acc2, MG, b_e2n, (float*)d_out);
    }
}